// Round 1
// 146.335 us; speedup vs baseline: 1.0101x; 1.0101x over previous
//
#include <hip/hip_runtime.h>
#include <hip/hip_bf16.h>

// Problem constants (from reference)
#define NN  100000   // nodes
#define DF  128      // feature dim per table
#define HD  64       // hidden dim
#define NS  250000   // samples

// ---------------------------------------------------------------------------
// Algebra (R6/R8): out[s] = w2 . relu(u'[src] + v[dst]), where
//   Pn = [in1|in2] @ B  (M=100000, K=256, N=128), bf16 (25.6 MB, L3-resident)
//   Pn[n][0:64]  = u'[n] = in1[n]@W1a + in2[n]@W1c + b1   (b1 folded)
//   Pn[n][64:128]= v [n] = in1[n]@W1b + in2[n]@W1d
//
// R13: edge frozen (R12 analysis: ~1M random 64-B lines through L2-miss->L3
// at ~0.8 lines/cyc/XCD; byte cuts don't change line count; fp8 would halve
// lines but blows absmax). GEMM restaged: R12 counters (MfmaUtil 5%, VALU 7%,
// HBM 23%, Occ 27.5%) say latency/transaction-bound, not BW-bound:
//   (a) old staging loads were 16 B/lane at 64-B stride = 64 lines/wave-instr
//       (4x the minimum). Now each staging instr covers contiguous 1 KB of
//       the 16-row in1/in2 block (16 lines/instr).
//   (b) NTILE 5->2: 3125 blocks -> 7 resident blocks/CU (LDS-capped) instead
//       of 4.88 (grid-capped).
//   (c) prefetch guarded (old code re-fetched tile0 on the last iter).
//   (d) fragment-slot LDS writes XOR-swizzled ((l*8)^(g<<3)), same XOR on the
//       b128 fragment reads: writes 8 banks x 2-way (free, m136), reads stay
//       a permutation of a contiguous 256-B phase (conflict-free).
//
// Verified MFMA layouts (gfx950, learn_hip m89/m91; R6-validated here):
//   A-frag: A[m=lane&15][k=(lane>>4)*8+j]   B-frag: B[n=lane&15][k=...]
//   C/D   : col=lane&15 (B/n side), row=(lane>>4)*4+reg (A/m side)
// LESSONS: train_sample is int32 on device; NS tail -> clamp+predicate;
// R9/R10: per-lane row-major loads scatter 16 lines/instr -> regression.
// ---------------------------------------------------------------------------

typedef __attribute__((ext_vector_type(8))) short bfrag;   // 8 bf16 = 4 VGPRs
typedef __attribute__((ext_vector_type(4))) float ffrag;   // 4 fp32 acc

__device__ __forceinline__ unsigned short bf16bits(float f) {
    __hip_bfloat16 b = __float2bfloat16(f);   // RNE
    return *(unsigned short*)&b;
}
__device__ __forceinline__ unsigned pack2(float a, float b) {
    return (unsigned)bf16bits(a) | ((unsigned)bf16bits(b) << 16);
}
__device__ __forceinline__ float bflo(unsigned u) {
    union { unsigned i; float f; } c; c.i = u << 16; return c.f;
}
__device__ __forceinline__ float bfhi(unsigned u) {
    union { unsigned i; float f; } c; c.i = u & 0xffff0000u; return c.f;
}
// lgkmcnt(0) only; vmcnt/expcnt left at max (gfx9 encoding) = 0xC07F
__device__ __forceinline__ void barrier_lgkm_only() {
    __builtin_amdgcn_s_waitcnt(0xC07F);
    __builtin_amdgcn_s_barrier();
}

// ---- prep: pack B (256x128) into fragment-ordered bf16; pack w2 bf16 ----
// Bf[tn][ks][lane][j]: n = tn*16+(lane&15), k = ks*32+(lane>>4)*8+j
__global__ __launch_bounds__(256) void prep_w1_kernel(
    const float* __restrict__ w1, const float* __restrict__ w2,
    unsigned short* __restrict__ Bf, unsigned short* __restrict__ w2bf)
{
    const int gid = blockIdx.x * 256 + threadIdx.x;
    if (gid >= 4096) {
        const int j = gid - 4096;
        if (j < HD) w2bf[j] = bf16bits(w2[j]);
        return;
    }
    const int lane = gid & 63;
    const int ks   = (gid >> 6) & 7;
    const int tn   = gid >> 9;

    const int n     = tn * 16 + (lane & 15);
    const int kbase = ks * 32 + (lane >> 4) * 8;
    const int col   = n & 63;

    uint4 u;
    unsigned p[4];
    #pragma unroll
    for (int jp = 0; jp < 4; ++jp) {
        float v[2];
        #pragma unroll
        for (int h = 0; h < 2; ++h) {
            const int k = kbase + jp * 2 + h;
            const int row = ((k >= 128) ? 256 : 0) + ((n >= 64) ? 128 : 0) + (k & 127);
            v[h] = w1[(size_t)row * HD + col];
        }
        p[jp] = pack2(v[0], v[1]);
    }
    u.x = p[0]; u.y = p[1]; u.z = p[2]; u.w = p[3];
    *(uint4*)(Bf + (size_t)gid * 8) = u;
}

#define NTILE 2      // tiles per block (R13: was 5; more blocks -> 7/CU resident)
#define NBLK  (NN / (16 * NTILE))   // 3125

// ---- phase 1 (R13): coalesced-staging pipelined MFMA GEMM ----
__global__ __launch_bounds__(256) void node_gemm_mfma(
    const float* __restrict__ in1,
    const float* __restrict__ in2,
    const unsigned short* __restrict__ Bf,
    const float* __restrict__ b1,
    unsigned short* __restrict__ Pn)         // [NN][128] bf16
{
    __shared__ unsigned short smem[8192 + 4 * 576];   // 2x8KB A dbuf + epilogue

    const int t    = threadIdx.x;
    const int lane = t & 63;
    const int w    = t >> 6;

    // B fragments for this wave's two column tiles (L2-hot, 16 KB/wave)
    bfrag bfr[2][8];
    #pragma unroll
    for (int ti = 0; ti < 2; ++ti) {
        const int tn = w * 2 + ti;
        #pragma unroll
        for (int ks = 0; ks < 8; ++ks)
            bfr[ti][ks] = *(const bfrag*)(Bf + ((size_t)(tn * 8 + ks) * 64 + lane) * 8);
    }
    float badd[2];
    #pragma unroll
    for (int ti = 0; ti < 2; ++ti) {
        const int nc = w * 32 + ti * 16 + (lane & 15);
        badd[ti] = (w < 2) ? b1[nc] : 0.f;
    }

    // Coalesced staging geometry: the 16-row A tile is two contiguous 8-KB
    // blocks (in1 rows m0..m0+15, in2 rows m0..m0+15). Piece i of thread t
    // covers floats [(i&1)*1024 + t*4, +4) of the in1 (i<2) / in2 (i>=2)
    // block -> every load instruction is 64 lanes x 16 B contiguous (16
    // lines/instr, was 64). Each 4-float piece lands at fragment slot:
    //   k=ks*32+g*8+j (g=(k>>3)&3, j=k&7 in {0,4}), l=m+16g,
    //   short-offset = ks*512 + ((l*8)^(g<<3)) + j      (XOR = bank swizzle)
    int ldsoff[4];
    #pragma unroll
    for (int i = 0; i < 4; ++i) {
        const int p  = (i & 1) * 256 + t;    // 16-B piece index within half
        const int m  = p >> 5;               // row 0..15
        const int c  = p & 31;               // piece within row
        const int k  = ((i >> 1) ? 128 : 0) + c * 4;
        const int ks = k >> 5;
        const int g  = (k >> 3) & 3;
        const int l  = m + 16 * g;
        ldsoff[i] = ks * 512 + ((l * 8) ^ (g << 3)) + (k & 7);
    }
    const int lane_off = (lane * 8) ^ ((lane >> 4) << 3);   // read-side XOR

    const int tile0 = blockIdx.x * NTILE;

    float4 cur[4], nxt[4];
    {
        const float* a1 = in1 + (size_t)tile0 * 16 * DF;
        const float* a2 = in2 + (size_t)tile0 * 16 * DF;
        cur[0] = *(const float4*)(a1 + t * 4);
        cur[1] = *(const float4*)(a1 + 1024 + t * 4);
        cur[2] = *(const float4*)(a2 + t * 4);
        cur[3] = *(const float4*)(a2 + 1024 + t * 4);
    }

    #pragma unroll
    for (int it = 0; it < NTILE; ++it) {
        const int m0 = (tile0 + it) * 16;

        if (it + 1 < NTILE) {   // guarded prefetch (no dead re-fetch of tile0)
            const float* a1 = in1 + (size_t)(m0 + 16) * DF;
            const float* a2 = in2 + (size_t)(m0 + 16) * DF;
            nxt[0] = *(const float4*)(a1 + t * 4);
            nxt[1] = *(const float4*)(a1 + 1024 + t * 4);
            nxt[2] = *(const float4*)(a2 + t * 4);
            nxt[3] = *(const float4*)(a2 + 1024 + t * 4);
        }

        unsigned short* abuf = &smem[(it & 1) * 4096];
        #pragma unroll
        for (int i = 0; i < 4; ++i) {
            uint2 u;
            u.x = pack2(cur[i].x, cur[i].y);
            u.y = pack2(cur[i].z, cur[i].w);
            *(uint2*)(&abuf[ldsoff[i]]) = u;   // ds_write_b64, <=2-way banks
        }

        barrier_lgkm_only();   // does NOT drain vmcnt: prefetch stays in flight

        ffrag acc[2] = {{0.f, 0.f, 0.f, 0.f}, {0.f, 0.f, 0.f, 0.f}};
        #pragma unroll
        for (int ks = 0; ks < 8; ++ks) {
            const bfrag af = *(const bfrag*)(&abuf[ks * 512 + lane_off]);
            acc[0] = __builtin_amdgcn_mfma_f32_16x16x32_bf16(af, bfr[0][ks], acc[0], 0, 0, 0);
            acc[1] = __builtin_amdgcn_mfma_f32_16x16x32_bf16(af, bfr[1][ks], acc[1], 0, 0, 0);
        }

        {
            unsigned short* ep = &smem[8192 + w * 576];   // 16 rows x 36
            const int col = lane & 15;
            const int rq  = lane >> 4;
            #pragma unroll
            for (int ti = 0; ti < 2; ++ti) {
                #pragma unroll
                for (int reg = 0; reg < 4; ++reg)
                    ep[(rq * 4 + reg) * 36 + ti * 16 + col] =
                        bf16bits(acc[ti][reg] + badd[ti]);
            }
            const int rowm = lane >> 2;
            const int seg  = lane & 3;
            const uint4 u = *(const uint4*)(&ep[rowm * 36 + seg * 8]);
            *(uint4*)(Pn + (size_t)(m0 + rowm) * 128 + w * 32 + seg * 8) = u;
        }

        #pragma unroll
        for (int i = 0; i < 4; ++i) cur[i] = nxt[i];
    }
}

// ---- phase 2 (R12, frozen): persistent gather MLP, dep-chain pipelined ----
// grid = 1024 blocks x 256 threads, 4 passes. Pass p of block b handles
// samples [ (p*1024 + b)*64, +64 ): 4 lanes/sample, 16 cols/lane.
// w2 slice hoisted to regs; next pass's ts load issues before current
// gathers are consumed -> every wave keeps ~5 independent VMEM in flight.
#define EBLK   1024
#define EPASS  4     // ceil(250000 / (1024*64)) = 4
__global__ __launch_bounds__(256) void edge_mlp_kernel(
    const unsigned short* __restrict__ Pn,
    const int*   __restrict__ ts,     // train_sample, int32
    const unsigned short* __restrict__ w2bf,   // 64 bf16
    float* __restrict__ out)          // (250000)
{
    const int t = threadIdx.x;
    const int q = t & 3;          // 16-col slice: cols q*16 .. q*16+15
    const int g = t >> 2;         // sample slot 0..63

    // hoist w2 slice (32 B) into registers once
    const uint4 w0 = *(const uint4*)(w2bf + q * 16);
    const uint4 w1v = *(const uint4*)(w2bf + q * 16 + 8);

    const int2* ts2 = (const int2*)ts;

    int sr = blockIdx.x * 64 + g;             // pass 0 sample
    int2 e = ts2[min(sr, NS - 1)];

    #pragma unroll
    for (int p = 0; p < EPASS; ++p) {
        // gathers for current sample (independent 16B loads)
        const unsigned short* up = Pn + (size_t)e.x * 128 + q * 16;
        const unsigned short* vp = Pn + (size_t)e.y * 128 + 64 + q * 16;
        const uint4 u0 = *(const uint4*)(up);
        const uint4 u1 = *(const uint4*)(up + 8);
        const uint4 v0 = *(const uint4*)(vp);
        const uint4 v1 = *(const uint4*)(vp + 8);

        // issue next pass's ts load BEFORE consuming the gathers
        const int sr_n = sr + EBLK * 64;
        int2 e_n;
        if (p + 1 < EPASS) e_n = ts2[min(sr_n, NS - 1)];

        float acc = 0.f, x;
        x = bflo(u0.x) + bflo(v0.x); x = x > 0.f ? x : 0.f; acc += x * bflo(w0.x);
        x = bfhi(u0.x) + bfhi(v0.x); x = x > 0.f ? x : 0.f; acc += x * bfhi(w0.x);
        x = bflo(u0.y) + bflo(v0.y); x = x > 0.f ? x : 0.f; acc += x * bflo(w0.y);
        x = bfhi(u0.y) + bfhi(v0.y); x = x > 0.f ? x : 0.f; acc += x * bfhi(w0.y);
        x = bflo(u0.z) + bflo(v0.z); x = x > 0.f ? x : 0.f; acc += x * bflo(w0.z);
        x = bfhi(u0.z) + bfhi(v0.z); x = x > 0.f ? x : 0.f; acc += x * bfhi(w0.z);
        x = bflo(u0.w) + bflo(v0.w); x = x > 0.f ? x : 0.f; acc += x * bflo(w0.w);
        x = bfhi(u0.w) + bfhi(v0.w); x = x > 0.f ? x : 0.f; acc += x * bfhi(w0.w);
        x = bflo(u1.x) + bflo(v1.x); x = x > 0.f ? x : 0.f; acc += x * bflo(w1v.x);
        x = bfhi(u1.x) + bfhi(v1.x); x = x > 0.f ? x : 0.f; acc += x * bfhi(w1v.x);
        x = bflo(u1.y) + bflo(v1.y); x = x > 0.f ? x : 0.f; acc += x * bflo(w1v.y);
        x = bfhi(u1.y) + bfhi(v1.y); x = x > 0.f ? x : 0.f; acc += x * bfhi(w1v.y);
        x = bflo(u1.z) + bflo(v1.z); x = x > 0.f ? x : 0.f; acc += x * bflo(w1v.z);
        x = bfhi(u1.z) + bfhi(v1.z); x = x > 0.f ? x : 0.f; acc += x * bfhi(w1v.z);
        x = bflo(u1.w) + bflo(v1.w); x = x > 0.f ? x : 0.f; acc += x * bflo(w1v.w);
        x = bfhi(u1.w) + bfhi(v1.w); x = x > 0.f ? x : 0.f; acc += x * bfhi(w1v.w);

        acc += __shfl_xor(acc, 1);
        acc += __shfl_xor(acc, 2);
        if (q == 0 && sr < NS) out[sr] = acc;

        sr = sr_n;
        e  = e_n;
    }
}

extern "C" void kernel_launch(void* const* d_in, const int* in_sizes, int n_in,
                              void* d_out, int out_size, void* d_ws, size_t ws_size,
                              hipStream_t stream) {
    const float* in1 = (const float*)d_in[0];
    const float* in2 = (const float*)d_in[1];
    const int*   ts  = (const int*)  d_in[2];
    const float* w1  = (const float*)d_in[3];
    const float* b1  = (const float*)d_in[4];
    const float* w2  = (const float*)d_in[5];
    float* out = (float*)d_out;

    unsigned short* Pn = (unsigned short*)d_ws;     // 100000*128*2 = 25.6 MB
    const size_t Pbytes = (size_t)NN * 128 * sizeof(unsigned short);
    unsigned short* Bf;                             // 64 KB packed-B fragments
    unsigned short* w2bf;                           // 128 B packed w2
    if (ws_size >= Pbytes + 65536 + 128) {
        Bf   = (unsigned short*)((char*)d_ws + Pbytes);
        w2bf = (unsigned short*)((char*)d_ws + Pbytes + 65536);
    } else {
        // fallback: borrow d_out front (fully overwritten by phase 2)
        Bf   = (unsigned short*)d_out;
        w2bf = (unsigned short*)((char*)d_out + 65536);
    }

    prep_w1_kernel<<<17, 256, 0, stream>>>(w1, w2, Bf, w2bf);
    node_gemm_mfma<<<NBLK, 256, 0, stream>>>(in1, in2, Bf, b1, Pn);
    edge_mlp_kernel<<<EBLK, 256, 0, stream>>>(Pn, ts, w2bf, out);
}